// Round 7
// baseline (387.496 us; speedup 1.0000x reference)
//
#include <hip/hip_runtime.h>
#include <hip/hip_bf16.h>
#include <stdint.h>

typedef __attribute__((ext_vector_type(8))) short bf16x8;
typedef __attribute__((ext_vector_type(4))) float f32x4;
typedef __attribute__((ext_vector_type(4))) float floatv4;
typedef __attribute__((ext_vector_type(8))) unsigned short ushortx8;

// fp32 -> bf16 round-to-nearest-even (finite inputs)
__device__ __forceinline__ unsigned short f2bf(float f) {
  union { float f; uint32_t u; } c; c.f = f;
  uint32_t u = c.u;
  uint32_t r = (u + 0x7FFFu + ((u >> 16) & 1u)) >> 16;
  return (unsigned short)r;
}

__global__ void cvt_f32_to_bf16(const float* __restrict__ src,
                                unsigned short* __restrict__ dst,
                                size_t n8) {
  size_t i = (size_t)blockIdx.x * blockDim.x + threadIdx.x;
  size_t stride = (size_t)gridDim.x * blockDim.x;
  for (size_t j = i; j < n8; j += stride) {
    floatv4 v0 = ((const floatv4*)src)[j * 2];
    floatv4 v1 = ((const floatv4*)src)[j * 2 + 1];
    ushortx8 o;
    o[0] = f2bf(v0[0]); o[1] = f2bf(v0[1]); o[2] = f2bf(v0[2]); o[3] = f2bf(v0[3]);
    o[4] = f2bf(v1[0]); o[5] = f2bf(v1[1]); o[6] = f2bf(v1[2]); o[7] = f2bf(v1[3]);
    ((ushortx8*)dst)[j] = o;
  }
}

// ---------------- 8-phase 256x256 bf16 GEMM (C = A * B^T + bias) ----------------
// 512 threads = 8 waves (2M x 4N), per-wave output 128x64.
// LDS 128 KiB: A[2buf][2half][128][64] + B[2buf][2half][128][64], bf16,
// read-side XOR swizzle (inverse pre-applied to global source of global_load_lds).
//
// REPHASED PIPELINE: each phase's ds_reads are consumed by the NEXT phase's
// quad (counted lgkmcnt), so the LDS grind of phase p overlaps the MFMA of
// phase p. Quad rotation: P0 runs Q3 of tile t-1 (reg-resident operands).
// STAGE placement rule: a region may be staged only >=1 barrier after the
// all-waves completion of its readers (reader lgkm-wait phase's closing BAR).
//   readers:  a0,b0 waited P1 -> A_s0/B_s0 region stage ok from P2
//             b1 waited P2    -> B_s1 region stage ok from P3
//             a1 waited P3    -> A_s1 region stage ok from P0 of t+1
// Stage schedule: P0: B_s0(t+1), A_s1(t+1); P2: A_s0(t+2); P3: B_s1(t+2).
// vmcnt: VMCNT(4) at P3 completes exactly tile t+1's 4 halves (8 loads).

#define BAR()    do { asm volatile("" ::: "memory"); __builtin_amdgcn_s_barrier(); asm volatile("" ::: "memory"); } while (0)
#define LGKMC(n) do { asm volatile("s_waitcnt lgkmcnt(" #n ")" ::: "memory"); __builtin_amdgcn_sched_barrier(0); } while (0)
#define VMCNT(n) asm volatile("s_waitcnt vmcnt(" #n ")" ::: "memory")

// stage one 128x64 half-tile (16 KiB) via 2x global_load_lds(16B) per thread
#define STAGE(ptr, mato, rcb, h, t_) do {                                          \
    const unsigned _lb = (mato) + (unsigned)((((t_) & 1) * 2 + (h)) * 8192);       \
    const int _k0 = (t_) << 6;                                                     \
    _Pragma("unroll")                                                              \
    for (int _l = 0; _l < 2; ++_l) {                                               \
      const int _idx = _l * 512 + tid;                                             \
      const int _r = _idx >> 3;                                                    \
      const int _ks = ((_idx & 7) * 8) ^ ((_r & 7) * 8);                           \
      __builtin_amdgcn_global_load_lds(                                            \
        (const __attribute__((address_space(1))) void*)((ptr) + (size_t)((rcb) + (h) * 128 + _r) * K + _k0 + _ks), \
        (__attribute__((address_space(3))) void*)&lds[_lb + (unsigned)((_l * 512 + widx * 64) * 8)], \
        16, 0, 0);                                                                 \
    }                                                                              \
  } while (0)

// read A quad q (8 x ds_read_b128): rows q*64 + mi*16 + l15 of wave's A-half
#define READ_A(dst, q, bo)                                                         \
  _Pragma("unroll")                                                                \
  for (int mi = 0; mi < 4; ++mi) {                                                 \
    const unsigned rb = Abase + (bo) + (unsigned)((((q) * 64) + mi * 16 + l15) * 64); \
    dst[mi * 2 + 0] = *(const bf16x8*)&lds[rb + koff0];                            \
    dst[mi * 2 + 1] = *(const bf16x8*)&lds[rb + koff1];                            \
  }

// read B n-half h (4 x ds_read_b128): rows brow + h*32 + ni*16 + l15 of wave's B-half
#define READ_B(dst, h, bo)                                                         \
  _Pragma("unroll")                                                                \
  for (int ni = 0; ni < 2; ++ni) {                                                 \
    const unsigned rb = Bbase + (bo) + (brow + (unsigned)((h) * 32 + ni * 16 + l15)) * 64u; \
    dst[ni * 2 + 0] = *(const bf16x8*)&lds[rb + koff0];                            \
    dst[ni * 2 + 1] = *(const bf16x8*)&lds[rb + koff1];                            \
  }

// one C-quadrant (q = M-quad, h = N-half) x K=64: 4mi x 2ni x 2kk = 16 MFMA
#define QUAD(aF, bF, q, h)                                                         \
  _Pragma("unroll")                                                                \
  for (int mi = 0; mi < 4; ++mi) {                                                 \
    _Pragma("unroll")                                                              \
    for (int ni = 0; ni < 2; ++ni) {                                               \
      acc[(q)*4+mi][(h)*2+ni] = __builtin_amdgcn_mfma_f32_16x16x32_bf16(           \
          aF[mi*2+0], bF[ni*2+0], acc[(q)*4+mi][(h)*2+ni], 0, 0, 0);               \
      acc[(q)*4+mi][(h)*2+ni] = __builtin_amdgcn_mfma_f32_16x16x32_bf16(           \
          aF[mi*2+1], bF[ni*2+1], acc[(q)*4+mi][(h)*2+ni], 0, 0, 0);               \
    }                                                                              \
  }

__global__ __launch_bounds__(512, 2)
void gemm8p_bt(const unsigned short* __restrict__ Ag,
               const unsigned short* __restrict__ Bg,
               const float* __restrict__ bias, float* __restrict__ C,
               int M, int N, int K)
{
  __shared__ __attribute__((aligned(128))) unsigned short lds[65536];   // 128 KiB
  const int tid  = threadIdx.x;
  const int lane = tid & 63;
  const int widx = tid >> 6;              // 8 waves
  const int wm   = widx >> 2;             // 0..1  (M)
  const int wn   = widx & 3;              // 0..3  (N)

  int bid = blockIdx.x;
  const int nwg = gridDim.x;
  if ((nwg & 7) == 0) { const int cpx = nwg >> 3; bid = (bid & 7) * cpx + (bid >> 3); }
  const int nTN = N >> 8;
  const int tm = bid / nTN, tn = bid - tm * nTN;
  const int row0 = tm << 8, col0 = tn << 8;

  const int l15 = lane & 15, l16 = lane >> 4;
  const unsigned m7    = (unsigned)((lane & 7) * 8);      // per-lane XOR mask (elems)
  const unsigned koff0 = ((unsigned)(l16 * 8)) ^ m7;      // kk=0 swizzled k-offset
  const unsigned koff1 = ((unsigned)(32 + l16 * 8)) ^ m7; // kk=1

  const int Kt = K >> 6;

  const unsigned Abase = (unsigned)(wm * 8192);               // + buf*16384
  const unsigned Bbase = 32768u + (unsigned)((wn >> 1) * 8192);
  const unsigned brow  = (unsigned)((wn & 1) * 64);

  f32x4 acc[8][4] = {};
  bf16x8 a0[8], a1[8], b0[4], b1[4];

  // ---- prologue: tile0 (4 halves) + {A_s0(1), B_s1(1)} (the 2-iter-ahead halves)
  // Loop invariant entering P0 of iter t: 4 loads in flight = {A_s0(t+1), B_s1(t+1)}.
  STAGE(Ag, 0u,     row0, 0, 0);
  STAGE(Ag, 0u,     row0, 1, 0);
  STAGE(Bg, 32768u, col0, 0, 0);
  STAGE(Bg, 32768u, col0, 1, 0);
  if (Kt > 1) {
    STAGE(Ag, 0u,     row0, 0, 1);
    STAGE(Bg, 32768u, col0, 1, 1);
    VMCNT(4);                 // tile0's 8 loads complete; tile1's 4 in flight
  } else {
    VMCNT(0);
  }
  BAR();                      // ALL waves drained tile0 -> P0 reads safe

  for (int t = 0; t < Kt; ++t) {
    const unsigned bufo = (unsigned)((t & 1) * 16384);

    // ---- P0: issue a0 reads; run Q3 of tile t-1 (reg-resident a1,b0);
    //          then issue b0 reads (b0 regs freed by Q3); stage B_s0/A_s1(t+1).
    READ_A(a0, 0, bufo);                          // 8 reads, grind under Q3
    __builtin_amdgcn_sched_barrier(0);            // keep reads ahead of the quad
    if (t > 0) {
      __builtin_amdgcn_s_setprio(1); QUAD(a1, b0, 1, 0); __builtin_amdgcn_s_setprio(0);
    }
    READ_B(b0, 0, bufo);                          // 4 reads (after Q3's last use of b0)
    if (t < Kt - 1) { STAGE(Bg, 32768u, col0, 0, t + 1); STAGE(Ag, 0u, row0, 1, t + 1); }
    BAR();

    // ---- P1: issue b1 reads; wait a0,b0 (counted, b1 stays in flight); Q0
    READ_B(b1, 1, bufo);                          // 4 reads, grind under Q0
    LGKMC(4);                                     // a0,b0 (12 oldest) done
    __builtin_amdgcn_s_setprio(1); QUAD(a0, b0, 0, 0); __builtin_amdgcn_s_setprio(0);
    BAR();

    // ---- P2: issue a1 reads; stage A_s0(t+2) [a0 readers done at P1-BAR];
    //          wait b1 (counted, a1 stays); Q1
    READ_A(a1, 1, bufo);                          // 8 reads, grind under Q1
    if (t < Kt - 2) STAGE(Ag, 0u, row0, 0, t + 2);
    LGKMC(8);                                     // b1 done (a1 in flight)
    __builtin_amdgcn_s_setprio(1); QUAD(a0, b1, 0, 1); __builtin_amdgcn_s_setprio(0);
    BAR();

    // ---- P3: stage B_s1(t+2) [b1 readers done at P2-BAR]; wait a1; Q2;
    //          VMCNT completes tile t+1 (all waves) before closing BAR.
    if (t < Kt - 2) STAGE(Bg, 32768u, col0, 1, t + 2);
    LGKMC(0);                                     // a1 done
    __builtin_amdgcn_s_setprio(1); QUAD(a1, b1, 1, 1); __builtin_amdgcn_s_setprio(0);
    if (t < Kt - 2)       { VMCNT(4); }   // completes tile t+1's 4 halves; t+2's 2 in flight
    else if (t == Kt - 2) { VMCNT(0); }   // drain before final tile
    BAR();
  }

  // ---- final Q3 of tile Kt-1 (operands a1,b0 in regs, drained at P3)
  __builtin_amdgcn_s_setprio(1); QUAD(a1, b0, 1, 0); __builtin_amdgcn_s_setprio(0);

  // ---- epilogue: C/D layout col=lane&15, row=(lane>>4)*4+j
  #pragma unroll
  for (int n = 0; n < 4; ++n) {
    const int col = col0 + wn * 64 + n * 16 + l15;
    const float bv = bias[col];
    #pragma unroll
    for (int mi8 = 0; mi8 < 8; ++mi8) {
      #pragma unroll
      for (int j = 0; j < 4; ++j) {
        const int row = row0 + wm * 128 + mi8 * 16 + l16 * 4 + j;
        C[(size_t)row * N + col] = acc[mi8][n][j] + bv;
      }
    }
  }
}

// ---------------- fallback: 128x128 2-phase kernel (round-1, verified) ----------------
template<bool BF16SRC>
__global__ __launch_bounds__(256)
void gemm_bt_kernel(const void* __restrict__ Ap, const void* __restrict__ Bp,
                    const float* __restrict__ bias, float* __restrict__ C,
                    int M, int N, int K)
{
  constexpr int BM = 128, BN = 128, BK = 64;
  __shared__ unsigned short As[BM * BK];
  __shared__ unsigned short Bs[BN * BK];

  const int nTN = N / BN;
  int bid = blockIdx.x;
  const int nwg = gridDim.x;
  if ((nwg & 7) == 0) { const int cpx = nwg >> 3; bid = (bid & 7) * cpx + (bid >> 3); }
  const int tm = bid / nTN, tn = bid % nTN;
  const int row0 = tm * BM, col0 = tn * BN;

  const int tid  = threadIdx.x;
  const int lane = tid & 63;
  const int wid  = tid >> 6;
  const int wm   = wid >> 1;
  const int wn   = wid & 1;

  f32x4 acc[4][4] = {};

  const unsigned short* A16 = (const unsigned short*)Ap;
  const unsigned short* B16 = (const unsigned short*)Bp;
  const float* A32 = (const float*)Ap;
  const float* B32 = (const float*)Bp;

  for (int k0 = 0; k0 < K; k0 += BK) {
    if constexpr (BF16SRC) {
      #pragma unroll
      for (int j = 0; j < 4; ++j) {
        const int c  = wid * 4 + j;
        const int r  = c * 8 + (lane >> 3);
        const int kk = (lane & 7) * 8;
        __builtin_amdgcn_global_load_lds(
            (const __attribute__((address_space(1))) void*)(A16 + (size_t)(row0 + r) * K + k0 + kk),
            (__attribute__((address_space(3))) void*)(&As[c * 512]), 16, 0, 0);
      }
      #pragma unroll
      for (int j = 0; j < 4; ++j) {
        const int c  = wid * 4 + j;
        const int r  = c * 8 + (lane >> 3);
        const int kk = (lane & 7) * 8;
        __builtin_amdgcn_global_load_lds(
            (const __attribute__((address_space(1))) void*)(B16 + (size_t)(col0 + r) * K + k0 + kk),
            (__attribute__((address_space(3))) void*)(&Bs[c * 512]), 16, 0, 0);
      }
    } else {
      #pragma unroll
      for (int j = 0; j < 4; ++j) {
        const int e = (j * 256 + tid) * 8;
        const int r = e >> 6, kk = e & 63;
        floatv4 v0 = *(const floatv4*)&A32[(size_t)(row0 + r) * K + k0 + kk];
        floatv4 v1 = *(const floatv4*)&A32[(size_t)(row0 + r) * K + k0 + kk + 4];
        ushortx8 o;
        o[0] = f2bf(v0[0]); o[1] = f2bf(v0[1]); o[2] = f2bf(v0[2]); o[3] = f2bf(v0[3]);
        o[4] = f2bf(v1[0]); o[5] = f2bf(v1[1]); o[6] = f2bf(v1[2]); o[7] = f2bf(v1[3]);
        *(ushortx8*)&As[e] = o;
      }
      #pragma unroll
      for (int j = 0; j < 4; ++j) {
        const int e = (j * 256 + tid) * 8;
        const int r = e >> 6, kk = e & 63;
        floatv4 v0 = *(const floatv4*)&B32[(size_t)(col0 + r) * K + k0 + kk];
        floatv4 v1 = *(const floatv4*)&B32[(size_t)(col0 + r) * K + k0 + kk + 4];
        ushortx8 o;
        o[0] = f2bf(v0[0]); o[1] = f2bf(v0[1]); o[2] = f2bf(v0[2]); o[3] = f2bf(v0[3]);
        o[4] = f2bf(v1[0]); o[5] = f2bf(v1[1]); o[6] = f2bf(v1[2]); o[7] = f2bf(v1[3]);
        *(ushortx8*)&Bs[e] = o;
      }
    }
    __syncthreads();

    #pragma unroll
    for (int kk = 0; kk < BK / 32; ++kk) {
      const int ko = kk * 32 + (lane >> 4) * 8;
      bf16x8 a[4], b[4];
      #pragma unroll
      for (int mi = 0; mi < 4; ++mi)
        a[mi] = *(const bf16x8*)&As[(wm * 64 + mi * 16 + (lane & 15)) * BK + ko];
      #pragma unroll
      for (int ni = 0; ni < 4; ++ni)
        b[ni] = *(const bf16x8*)&Bs[(wn * 64 + ni * 16 + (lane & 15)) * BK + ko];
      #pragma unroll
      for (int mi = 0; mi < 4; ++mi)
        #pragma unroll
        for (int ni = 0; ni < 4; ++ni)
          acc[mi][ni] = __builtin_amdgcn_mfma_f32_16x16x32_bf16(a[mi], b[ni], acc[mi][ni], 0, 0, 0);
    }
    __syncthreads();
  }

  #pragma unroll
  for (int mi = 0; mi < 4; ++mi) {
    #pragma unroll
    for (int ni = 0; ni < 4; ++ni) {
      const int col = col0 + wn * 64 + ni * 16 + (lane & 15);
      const float bv = bias[col];
      #pragma unroll
      for (int j = 0; j < 4; ++j) {
        const int row = row0 + wm * 64 + mi * 16 + (lane >> 4) * 4 + j;
        C[(size_t)row * N + col] = acc[mi][ni][j] + bv;
      }
    }
  }
}

extern "C" void kernel_launch(void* const* d_in, const int* in_sizes, int n_in,
                              void* d_out, int out_size, void* d_ws, size_t ws_size,
                              hipStream_t stream) {
  const float* x = (const float*)d_in[0];
  const float* w = (const float*)d_in[1];
  const float* b = (const float*)d_in[2];
  float* out = (float*)d_out;

  const int N = in_sizes[2];            // 4096
  const int K = in_sizes[1] / N;        // 4096
  const int M = in_sizes[0] / K;        // 8192

  const size_t needed = ((size_t)M * K + (size_t)N * K) * sizeof(unsigned short);

  if (ws_size >= needed) {
    unsigned short* Abf = (unsigned short*)d_ws;
    unsigned short* Bbf = Abf + (size_t)M * K;
    cvt_f32_to_bf16<<<2048, 256, 0, stream>>>(x, Abf, (size_t)M * K / 8);
    cvt_f32_to_bf16<<<2048, 256, 0, stream>>>(w, Bbf, (size_t)N * K / 8);
    if ((M % 256) == 0 && (N % 256) == 0 && (K % 64) == 0 && K >= 192) {
      const int grid = (M / 256) * (N / 256);
      gemm8p_bt<<<grid, 512, 0, stream>>>(Abf, Bbf, b, out, M, N, K);
    } else {
      const int grid = (M / 128) * (N / 128);
      gemm_bt_kernel<true><<<grid, 256, 0, stream>>>(Abf, Bbf, b, out, M, N, K);
    }
  } else {
    const int grid = (M / 128) * (N / 128);
    gemm_bt_kernel<false><<<grid, 256, 0, stream>>>(x, w, b, out, M, N, K);
  }
}

// Round 8
// 307.561 us; speedup vs baseline: 1.2599x; 1.2599x over previous
//
#include <hip/hip_runtime.h>
#include <hip/hip_bf16.h>
#include <stdint.h>

typedef __attribute__((ext_vector_type(8))) short bf16x8;
typedef __attribute__((ext_vector_type(4))) float f32x4;
typedef __attribute__((ext_vector_type(4))) float floatv4;
typedef __attribute__((ext_vector_type(8))) unsigned short ushortx8;

// fp32 -> bf16 round-to-nearest-even (finite inputs)
__device__ __forceinline__ unsigned short f2bf(float f) {
  union { float f; uint32_t u; } c; c.f = f;
  uint32_t u = c.u;
  uint32_t r = (u + 0x7FFFu + ((u >> 16) & 1u)) >> 16;
  return (unsigned short)r;
}

__global__ void cvt_f32_to_bf16(const float* __restrict__ src,
                                unsigned short* __restrict__ dst,
                                size_t n8) {
  size_t i = (size_t)blockIdx.x * blockDim.x + threadIdx.x;
  size_t stride = (size_t)gridDim.x * blockDim.x;
  for (size_t j = i; j < n8; j += stride) {
    floatv4 v0 = ((const floatv4*)src)[j * 2];
    floatv4 v1 = ((const floatv4*)src)[j * 2 + 1];
    ushortx8 o;
    o[0] = f2bf(v0[0]); o[1] = f2bf(v0[1]); o[2] = f2bf(v0[2]); o[3] = f2bf(v0[3]);
    o[4] = f2bf(v1[0]); o[5] = f2bf(v1[1]); o[6] = f2bf(v1[2]); o[7] = f2bf(v1[3]);
    ((ushortx8*)dst)[j] = o;
  }
}

// ---------------- 4-barrier 256x256 bf16 GEMM (C = A * B^T + bias) ----------------
// 512 threads = 8 waves (2M x 4N), per-wave output 128x64.
// LDS 128 KiB: A[2buf][2half][128][64] + B[2buf][2half][128][64], bf16,
// read-side XOR swizzle (inverse pre-applied to global source of global_load_lds).
//
// ONE barrier per phase: [reads; stage; MFMA; BAR]. No explicit lgkm waits —
// the compiler emits fine-grained lgkmcnt so early MFMAs overlap the tail of
// the read grind (m97 disasm behavior). Correctness ledger (round-5 derived):
//  - a region is STAGEd only >=1 closing-barrier after its last consuming QUAD
//    (consumption implies the wave's ds_reads retired before it passed that BAR):
//      a0 consumed P1, a1 consumed P2  -> A_s0/A_s1(t+2) staged P3   (1-2 BARs)
//      b1 consumed P2                  -> B_s1(t+2) staged P3        (1 BAR)
//      b0 consumed P3                  -> B_s0(t+2) staged P0 of t+1 (1 BAR)
//  - same-phase ds_read vs global_load_lds to one region is UNORDERED (different
//    HW queues) -> never stage a region read in the same phase.
//  - vmcnt: in-flight entering P0 = 6 {B_s1,A_s0,A_s1}(t+1); P0 +2 (B_s0(t+1));
//    P3 +6 (t+2 halves) = 14; VMCNT(6) completes the 8 oldest = tile t+1 exactly.
//    vmcnt is per-wave: reads of staged data only after VMCNT+BAR (all waves).

#define BAR()    do { asm volatile("" ::: "memory"); __builtin_amdgcn_s_barrier(); asm volatile("" ::: "memory"); } while (0)
#define VMCNT(n) asm volatile("s_waitcnt vmcnt(" #n ")" ::: "memory")

// stage one 128x64 half-tile (16 KiB) via 2x global_load_lds(16B) per thread
#define STAGE(ptr, mato, rcb, h, t_) do {                                          \
    const unsigned _lb = (mato) + (unsigned)((((t_) & 1) * 2 + (h)) * 8192);       \
    const int _k0 = (t_) << 6;                                                     \
    _Pragma("unroll")                                                              \
    for (int _l = 0; _l < 2; ++_l) {                                               \
      const int _idx = _l * 512 + tid;                                             \
      const int _r = _idx >> 3;                                                    \
      const int _ks = ((_idx & 7) * 8) ^ ((_r & 7) * 8);                           \
      __builtin_amdgcn_global_load_lds(                                            \
        (const __attribute__((address_space(1))) void*)((ptr) + (size_t)((rcb) + (h) * 128 + _r) * K + _k0 + _ks), \
        (__attribute__((address_space(3))) void*)&lds[_lb + (unsigned)((_l * 512 + widx * 64) * 8)], \
        16, 0, 0);                                                                 \
    }                                                                              \
  } while (0)

// read A quad q (8 x ds_read_b128): rows q*64 + mi*16 + l15 of wave's A-half
#define READ_A(dst, q, bo)                                                         \
  _Pragma("unroll")                                                                \
  for (int mi = 0; mi < 4; ++mi) {                                                 \
    const unsigned rb = Abase + (bo) + (unsigned)((((q) * 64) + mi * 16 + l15) * 64); \
    dst[mi * 2 + 0] = *(const bf16x8*)&lds[rb + koff0];                            \
    dst[mi * 2 + 1] = *(const bf16x8*)&lds[rb + koff1];                            \
  }

// read B n-half h (4 x ds_read_b128): rows brow + h*32 + ni*16 + l15 of wave's B-half
#define READ_B(dst, h, bo)                                                         \
  _Pragma("unroll")                                                                \
  for (int ni = 0; ni < 2; ++ni) {                                                 \
    const unsigned rb = Bbase + (bo) + (brow + (unsigned)((h) * 32 + ni * 16 + l15)) * 64u; \
    dst[ni * 2 + 0] = *(const bf16x8*)&lds[rb + koff0];                            \
    dst[ni * 2 + 1] = *(const bf16x8*)&lds[rb + koff1];                            \
  }

// one C-quadrant (q = M-quad, h = N-half) x K=64: 4mi x 2ni x 2kk = 16 MFMA
#define QUAD(aF, bF, q, h)                                                         \
  _Pragma("unroll")                                                                \
  for (int mi = 0; mi < 4; ++mi) {                                                 \
    _Pragma("unroll")                                                              \
    for (int ni = 0; ni < 2; ++ni) {                                               \
      acc[(q)*4+mi][(h)*2+ni] = __builtin_amdgcn_mfma_f32_16x16x32_bf16(           \
          aF[mi*2+0], bF[ni*2+0], acc[(q)*4+mi][(h)*2+ni], 0, 0, 0);               \
      acc[(q)*4+mi][(h)*2+ni] = __builtin_amdgcn_mfma_f32_16x16x32_bf16(           \
          aF[mi*2+1], bF[ni*2+1], acc[(q)*4+mi][(h)*2+ni], 0, 0, 0);               \
    }                                                                              \
  }

__global__ __launch_bounds__(512, 2)
void gemm8p_bt(const unsigned short* __restrict__ Ag,
               const unsigned short* __restrict__ Bg,
               const float* __restrict__ bias, float* __restrict__ C,
               int M, int N, int K)
{
  __shared__ __attribute__((aligned(128))) unsigned short lds[65536];   // 128 KiB
  const int tid  = threadIdx.x;
  const int lane = tid & 63;
  const int widx = tid >> 6;              // 8 waves
  const int wm   = widx >> 2;             // 0..1  (M)
  const int wn   = widx & 3;              // 0..3  (N)

  int bid = blockIdx.x;
  const int nwg = gridDim.x;
  if ((nwg & 7) == 0) { const int cpx = nwg >> 3; bid = (bid & 7) * cpx + (bid >> 3); }
  const int nTN = N >> 8;
  const int tm = bid / nTN, tn = bid - tm * nTN;
  const int row0 = tm << 8, col0 = tn << 8;

  const int l15 = lane & 15, l16 = lane >> 4;
  const unsigned m7    = (unsigned)((lane & 7) * 8);      // per-lane XOR mask (elems)
  const unsigned koff0 = ((unsigned)(l16 * 8)) ^ m7;      // kk=0 swizzled k-offset
  const unsigned koff1 = ((unsigned)(32 + l16 * 8)) ^ m7; // kk=1

  const int Kt = K >> 6;

  const unsigned Abase = (unsigned)(wm * 8192);               // + buf*16384
  const unsigned Bbase = 32768u + (unsigned)((wn >> 1) * 8192);
  const unsigned brow  = (unsigned)((wn & 1) * 64);

  f32x4 acc[8][4] = {};
  bf16x8 a0[8], a1[8], b0[4], b1[4];

  // ---- prologue: tile0 (4 halves) + {B_s1(1), A_s0(1), A_s1(1)} ----
  // Invariant entering each iteration: 6 loads in flight = {B_s1(t+1), A_s0(t+1), A_s1(t+1)}.
  STAGE(Ag, 0u,     row0, 0, 0);
  STAGE(Ag, 0u,     row0, 1, 0);
  STAGE(Bg, 32768u, col0, 0, 0);
  STAGE(Bg, 32768u, col0, 1, 0);
  if (Kt > 1) {
    STAGE(Bg, 32768u, col0, 1, 1);
    STAGE(Ag, 0u,     row0, 0, 1);
    STAGE(Ag, 0u,     row0, 1, 1);
    VMCNT(6);                 // tile0's 8 loads complete; tile1's 6 in flight
  } else {
    VMCNT(0);
  }
  BAR();                      // ALL waves drained tile0 -> P0 reads safe

  for (int t = 0; t < Kt; ++t) {
    const unsigned bufo = (unsigned)((t & 1) * 16384);

    // ---- P0: read b0(4)+a0(8) (B first: first MFMA ready after ~6 reads);
    //          stage B_s0(t+1) [buf t+1, last consumed P0 of t-1]; Q(a0,b0); BAR
    READ_B(b0, 0, bufo);
    READ_A(a0, 0, bufo);
    if (t < Kt - 1) STAGE(Bg, 32768u, col0, 0, t + 1);
    __builtin_amdgcn_s_setprio(1); QUAD(a0, b0, 0, 0); __builtin_amdgcn_s_setprio(0);
    BAR();

    // ---- P1: read b1(4); Q(a0,b1); BAR
    READ_B(b1, 1, bufo);
    __builtin_amdgcn_s_setprio(1); QUAD(a0, b1, 0, 1); __builtin_amdgcn_s_setprio(0);
    BAR();

    // ---- P2: read a1(8); Q(a1,b1); BAR
    READ_A(a1, 1, bufo);
    __builtin_amdgcn_s_setprio(1); QUAD(a1, b1, 1, 1); __builtin_amdgcn_s_setprio(0);
    BAR();

    // ---- P3: stage B_s1(t+2) [b1 consumed P2], A_s0(t+2) [a0 consumed P1],
    //          A_s1(t+2) [a1 consumed P2]; Q(a1,b0); VMCNT; BAR
    if (t < Kt - 2) {
      STAGE(Bg, 32768u, col0, 1, t + 2);
      STAGE(Ag, 0u,     row0, 0, t + 2);
      STAGE(Ag, 0u,     row0, 1, t + 2);
    }
    __builtin_amdgcn_s_setprio(1); QUAD(a1, b0, 1, 0); __builtin_amdgcn_s_setprio(0);
    if (t < Kt - 2)       { VMCNT(6); }   // completes tile t+1's 4 halves; t+2's 6 in flight
    else if (t == Kt - 2) { VMCNT(0); }   // drain before final tile
    BAR();
  }

  // ---- epilogue: C/D layout col=lane&15, row=(lane>>4)*4+j
  #pragma unroll
  for (int n = 0; n < 4; ++n) {
    const int col = col0 + wn * 64 + n * 16 + l15;
    const float bv = bias[col];
    #pragma unroll
    for (int mi8 = 0; mi8 < 8; ++mi8) {
      #pragma unroll
      for (int j = 0; j < 4; ++j) {
        const int row = row0 + wm * 128 + mi8 * 16 + l16 * 4 + j;
        C[(size_t)row * N + col] = acc[mi8][n][j] + bv;
      }
    }
  }
}

// ---------------- fallback: 128x128 2-phase kernel (round-1, verified) ----------------
template<bool BF16SRC>
__global__ __launch_bounds__(256)
void gemm_bt_kernel(const void* __restrict__ Ap, const void* __restrict__ Bp,
                    const float* __restrict__ bias, float* __restrict__ C,
                    int M, int N, int K)
{
  constexpr int BM = 128, BN = 128, BK = 64;
  __shared__ unsigned short As[BM * BK];
  __shared__ unsigned short Bs[BN * BK];

  const int nTN = N / BN;
  int bid = blockIdx.x;
  const int nwg = gridDim.x;
  if ((nwg & 7) == 0) { const int cpx = nwg >> 3; bid = (bid & 7) * cpx + (bid >> 3); }
  const int tm = bid / nTN, tn = bid % nTN;
  const int row0 = tm * BM, col0 = tn * BN;

  const int tid  = threadIdx.x;
  const int lane = tid & 63;
  const int wid  = tid >> 6;
  const int wm   = wid >> 1;
  const int wn   = wid & 1;

  f32x4 acc[4][4] = {};

  const unsigned short* A16 = (const unsigned short*)Ap;
  const unsigned short* B16 = (const unsigned short*)Bp;
  const float* A32 = (const float*)Ap;
  const float* B32 = (const float*)Bp;

  for (int k0 = 0; k0 < K; k0 += BK) {
    if constexpr (BF16SRC) {
      #pragma unroll
      for (int j = 0; j < 4; ++j) {
        const int c  = wid * 4 + j;
        const int r  = c * 8 + (lane >> 3);
        const int kk = (lane & 7) * 8;
        __builtin_amdgcn_global_load_lds(
            (const __attribute__((address_space(1))) void*)(A16 + (size_t)(row0 + r) * K + k0 + kk),
            (__attribute__((address_space(3))) void*)(&As[c * 512]), 16, 0, 0);
      }
      #pragma unroll
      for (int j = 0; j < 4; ++j) {
        const int c  = wid * 4 + j;
        const int r  = c * 8 + (lane >> 3);
        const int kk = (lane & 7) * 8;
        __builtin_amdgcn_global_load_lds(
            (const __attribute__((address_space(1))) void*)(B16 + (size_t)(col0 + r) * K + k0 + kk),
            (__attribute__((address_space(3))) void*)(&Bs[c * 512]), 16, 0, 0);
      }
    } else {
      #pragma unroll
      for (int j = 0; j < 4; ++j) {
        const int e = (j * 256 + tid) * 8;
        const int r = e >> 6, kk = e & 63;
        floatv4 v0 = *(const floatv4*)&A32[(size_t)(row0 + r) * K + k0 + kk];
        floatv4 v1 = *(const floatv4*)&A32[(size_t)(row0 + r) * K + k0 + kk + 4];
        ushortx8 o;
        o[0] = f2bf(v0[0]); o[1] = f2bf(v0[1]); o[2] = f2bf(v0[2]); o[3] = f2bf(v0[3]);
        o[4] = f2bf(v1[0]); o[5] = f2bf(v1[1]); o[6] = f2bf(v1[2]); o[7] = f2bf(v1[3]);
        *(ushortx8*)&As[e] = o;
      }
      #pragma unroll
      for (int j = 0; j < 4; ++j) {
        const int e = (j * 256 + tid) * 8;
        const int r = e >> 6, kk = e & 63;
        floatv4 v0 = *(const floatv4*)&B32[(size_t)(col0 + r) * K + k0 + kk];
        floatv4 v1 = *(const floatv4*)&B32[(size_t)(col0 + r) * K + k0 + kk + 4];
        ushortx8 o;
        o[0] = f2bf(v0[0]); o[1] = f2bf(v0[1]); o[2] = f2bf(v0[2]); o[3] = f2bf(v0[3]);
        o[4] = f2bf(v1[0]); o[5] = f2bf(v1[1]); o[6] = f2bf(v1[2]); o[7] = f2bf(v1[3]);
        *(ushortx8*)&Bs[e] = o;
      }
    }
    __syncthreads();

    #pragma unroll
    for (int kk = 0; kk < BK / 32; ++kk) {
      const int ko = kk * 32 + (lane >> 4) * 8;
      bf16x8 a[4], b[4];
      #pragma unroll
      for (int mi = 0; mi < 4; ++mi)
        a[mi] = *(const bf16x8*)&As[(wm * 64 + mi * 16 + (lane & 15)) * BK + ko];
      #pragma unroll
      for (int ni = 0; ni < 4; ++ni)
        b[ni] = *(const bf16x8*)&Bs[(wn * 64 + ni * 16 + (lane & 15)) * BK + ko];
      #pragma unroll
      for (int mi = 0; mi < 4; ++mi)
        #pragma unroll
        for (int ni = 0; ni < 4; ++ni)
          acc[mi][ni] = __builtin_amdgcn_mfma_f32_16x16x32_bf16(a[mi], b[ni], acc[mi][ni], 0, 0, 0);
    }
    __syncthreads();
  }

  #pragma unroll
  for (int mi = 0; mi < 4; ++mi) {
    #pragma unroll
    for (int ni = 0; ni < 4; ++ni) {
      const int col = col0 + wn * 64 + ni * 16 + (lane & 15);
      const float bv = bias[col];
      #pragma unroll
      for (int j = 0; j < 4; ++j) {
        const int row = row0 + wm * 64 + mi * 16 + (lane >> 4) * 4 + j;
        C[(size_t)row * N + col] = acc[mi][ni][j] + bv;
      }
    }
  }
}

extern "C" void kernel_launch(void* const* d_in, const int* in_sizes, int n_in,
                              void* d_out, int out_size, void* d_ws, size_t ws_size,
                              hipStream_t stream) {
  const float* x = (const float*)d_in[0];
  const float* w = (const float*)d_in[1];
  const float* b = (const float*)d_in[2];
  float* out = (float*)d_out;

  const int N = in_sizes[2];            // 4096
  const int K = in_sizes[1] / N;        // 4096
  const int M = in_sizes[0] / K;        // 8192

  const size_t needed = ((size_t)M * K + (size_t)N * K) * sizeof(unsigned short);

  if (ws_size >= needed) {
    unsigned short* Abf = (unsigned short*)d_ws;
    unsigned short* Bbf = Abf + (size_t)M * K;
    cvt_f32_to_bf16<<<2048, 256, 0, stream>>>(x, Abf, (size_t)M * K / 8);
    cvt_f32_to_bf16<<<2048, 256, 0, stream>>>(w, Bbf, (size_t)N * K / 8);
    if ((M % 256) == 0 && (N % 256) == 0 && (K % 64) == 0 && K >= 192) {
      const int grid = (M / 256) * (N / 256);
      gemm8p_bt<<<grid, 512, 0, stream>>>(Abf, Bbf, b, out, M, N, K);
    } else {
      const int grid = (M / 128) * (N / 128);
      gemm_bt_kernel<true><<<grid, 256, 0, stream>>>(Abf, Bbf, b, out, M, N, K);
    }
  } else {
    const int grid = (M / 128) * (N / 128);
    gemm_bt_kernel<false><<<grid, 256, 0, stream>>>(x, w, b, out, M, N, K);
  }
}

// Round 9
// 306.878 us; speedup vs baseline: 1.2627x; 1.0022x over previous
//
#include <hip/hip_runtime.h>
#include <hip/hip_bf16.h>
#include <stdint.h>

typedef __attribute__((ext_vector_type(8))) short bf16x8;
typedef __attribute__((ext_vector_type(4))) float f32x4;
typedef __attribute__((ext_vector_type(4))) float floatv4;
typedef __attribute__((ext_vector_type(8))) unsigned short ushortx8;

// fp32 -> bf16 round-to-nearest-even (finite inputs)
__device__ __forceinline__ unsigned short f2bf(float f) {
  union { float f; uint32_t u; } c; c.f = f;
  uint32_t u = c.u;
  uint32_t r = (u + 0x7FFFu + ((u >> 16) & 1u)) >> 16;
  return (unsigned short)r;
}

__global__ void cvt_f32_to_bf16(const float* __restrict__ src,
                                unsigned short* __restrict__ dst,
                                size_t n8) {
  size_t i = (size_t)blockIdx.x * blockDim.x + threadIdx.x;
  size_t stride = (size_t)gridDim.x * blockDim.x;
  for (size_t j = i; j < n8; j += stride) {
    floatv4 v0 = ((const floatv4*)src)[j * 2];
    floatv4 v1 = ((const floatv4*)src)[j * 2 + 1];
    ushortx8 o;
    o[0] = f2bf(v0[0]); o[1] = f2bf(v0[1]); o[2] = f2bf(v0[2]); o[3] = f2bf(v0[3]);
    o[4] = f2bf(v1[0]); o[5] = f2bf(v1[1]); o[6] = f2bf(v1[2]); o[7] = f2bf(v1[3]);
    ((ushortx8*)dst)[j] = o;
  }
}

// ---------------- read-ahead 256x256 bf16 GEMM (C = A * B^T + bias) ----------------
// 512 threads = 8 waves (2M x 4N), per-wave output 128x64. LDS 128 KiB -> 1 block/CU,
// so all overlap must be engineered intra-block: every ds_read batch is issued ONE
// PHASE BEFORE its consuming quad and grinds under the current quad's MFMA.
//
// Phases (4 barriers per K-tile):
//  P0: read b1 (for P1); stage B_s0(t+1); Q(a0,b0); BAR
//  P1: read a1 (for P2); Q(a0,b1); BAR
//  P2: Q(a1,b1) [no reads]; BAR
//  P3: stage B_s1/A_s0/A_s1(t+2); VMCNT(6); BAR(mid);
//      read a0(next tile); Q(a1,b0); read b0(next tile)   [no end barrier]
//
// Ledger: vmcnt in-flight 6 -> +2(P0) -> +6(P3) = 14; VMCNT(6) completes exactly
// tile t+1's 8 loads (every wave, before the mid-BAR) -> next-tile reads safe.
// WAR: each staged region's reads retired >=1 barrier earlier (b1:P0-issued,
// lgkm-retired before P1 quad; a1: before P2 quad; a0: before P0 quad; b0: P0 of t).
// No-end-barrier skew audit: P0-of-t+1 ops touch only regions retired >=1 BAR ago.

#define BAR()    do { asm volatile("" ::: "memory"); __builtin_amdgcn_s_barrier(); asm volatile("" ::: "memory"); } while (0)
#define VMCNT(n) asm volatile("s_waitcnt vmcnt(" #n ")" ::: "memory")
#define SCHEDB() __builtin_amdgcn_sched_barrier(0)

// stage one 128x64 half-tile (16 KiB) via 2x global_load_lds(16B) per thread
#define STAGE(ptr, mato, rcb, h, t_) do {                                          \
    const unsigned _lb = (mato) + (unsigned)((((t_) & 1) * 2 + (h)) * 8192);       \
    const int _k0 = (t_) << 6;                                                     \
    _Pragma("unroll")                                                              \
    for (int _l = 0; _l < 2; ++_l) {                                               \
      const int _idx = _l * 512 + tid;                                             \
      const int _r = _idx >> 3;                                                    \
      const int _ks = ((_idx & 7) * 8) ^ ((_r & 7) * 8);                           \
      __builtin_amdgcn_global_load_lds(                                            \
        (const __attribute__((address_space(1))) void*)((ptr) + (size_t)((rcb) + (h) * 128 + _r) * K + _k0 + _ks), \
        (__attribute__((address_space(3))) void*)&lds[_lb + (unsigned)((_l * 512 + widx * 64) * 8)], \
        16, 0, 0);                                                                 \
    }                                                                              \
  } while (0)

// read A quad q (8 x ds_read_b128): rows q*64 + mi*16 + l15 of wave's A-half
#define READ_A(dst, q, bo)                                                         \
  _Pragma("unroll")                                                                \
  for (int mi = 0; mi < 4; ++mi) {                                                 \
    const unsigned rb = Abase + (bo) + (unsigned)((((q) * 64) + mi * 16 + l15) * 64); \
    dst[mi * 2 + 0] = *(const bf16x8*)&lds[rb + koff0];                            \
    dst[mi * 2 + 1] = *(const bf16x8*)&lds[rb + koff1];                            \
  }

// read B n-half h (4 x ds_read_b128): rows brow + h*32 + ni*16 + l15 of wave's B-half
#define READ_B(dst, h, bo)                                                         \
  _Pragma("unroll")                                                                \
  for (int ni = 0; ni < 2; ++ni) {                                                 \
    const unsigned rb = Bbase + (bo) + (brow + (unsigned)((h) * 32 + ni * 16 + l15)) * 64u; \
    dst[ni * 2 + 0] = *(const bf16x8*)&lds[rb + koff0];                            \
    dst[ni * 2 + 1] = *(const bf16x8*)&lds[rb + koff1];                            \
  }

// one C-quadrant (q = M-quad, h = N-half) x K=64: 4mi x 2ni x 2kk = 16 MFMA
#define QUAD(aF, bF, q, h)                                                         \
  _Pragma("unroll")                                                                \
  for (int mi = 0; mi < 4; ++mi) {                                                 \
    _Pragma("unroll")                                                              \
    for (int ni = 0; ni < 2; ++ni) {                                               \
      acc[(q)*4+mi][(h)*2+ni] = __builtin_amdgcn_mfma_f32_16x16x32_bf16(           \
          aF[mi*2+0], bF[ni*2+0], acc[(q)*4+mi][(h)*2+ni], 0, 0, 0);               \
      acc[(q)*4+mi][(h)*2+ni] = __builtin_amdgcn_mfma_f32_16x16x32_bf16(           \
          aF[mi*2+1], bF[ni*2+1], acc[(q)*4+mi][(h)*2+ni], 0, 0, 0);               \
    }                                                                              \
  }

__global__ __launch_bounds__(512, 2)
void gemm8p_bt(const unsigned short* __restrict__ Ag,
               const unsigned short* __restrict__ Bg,
               const float* __restrict__ bias, float* __restrict__ C,
               int M, int N, int K)
{
  __shared__ __attribute__((aligned(128))) unsigned short lds[65536];   // 128 KiB
  const int tid  = threadIdx.x;
  const int lane = tid & 63;
  const int widx = tid >> 6;              // 8 waves
  const int wm   = widx >> 2;             // 0..1  (M)
  const int wn   = widx & 3;              // 0..3  (N)

  int bid = blockIdx.x;
  const int nwg = gridDim.x;
  if ((nwg & 7) == 0) { const int cpx = nwg >> 3; bid = (bid & 7) * cpx + (bid >> 3); }
  const int nTN = N >> 8;
  const int tm = bid / nTN, tn = bid - tm * nTN;
  const int row0 = tm << 8, col0 = tn << 8;

  const int l15 = lane & 15, l16 = lane >> 4;
  const unsigned m7    = (unsigned)((lane & 7) * 8);      // per-lane XOR mask (elems)
  const unsigned koff0 = ((unsigned)(l16 * 8)) ^ m7;      // kk=0 swizzled k-offset
  const unsigned koff1 = ((unsigned)(32 + l16 * 8)) ^ m7; // kk=1

  const int Kt = K >> 6;

  const unsigned Abase = (unsigned)(wm * 8192);               // + buf*16384
  const unsigned Bbase = 32768u + (unsigned)((wn >> 1) * 8192);
  const unsigned brow  = (unsigned)((wn & 1) * 64);

  f32x4 acc[8][4] = {};
  bf16x8 a0[8], a1[8], b0[4], b1[4];

  // ---- prologue: tile0 (4 halves) + {B_s1(1), A_s0(1), A_s1(1)};
  //      then pre-read tile0's a0,b0 (after VMCNT+BAR -> cross-wave safe).
  STAGE(Ag, 0u,     row0, 0, 0);
  STAGE(Ag, 0u,     row0, 1, 0);
  STAGE(Bg, 32768u, col0, 0, 0);
  STAGE(Bg, 32768u, col0, 1, 0);
  if (Kt > 1) {
    STAGE(Bg, 32768u, col0, 1, 1);
    STAGE(Ag, 0u,     row0, 0, 1);
    STAGE(Ag, 0u,     row0, 1, 1);
    VMCNT(6);                 // tile0's 8 loads complete; tile1's 6 in flight
  } else {
    VMCNT(0);
  }
  BAR();                      // ALL waves drained tile0
  READ_A(a0, 0, 0u);
  READ_B(b0, 0, 0u);

  for (int t = 0; t < Kt; ++t) {
    const unsigned bufo  = (unsigned)((t & 1) * 16384);
    const unsigned nbufo = (unsigned)(((t + 1) & 1) * 16384);

    // ---- P0: read b1 (for P1, grinds under Q0); stage B_s0(t+1); Q(a0,b0); BAR
    READ_B(b1, 1, bufo);
    if (t < Kt - 1) STAGE(Bg, 32768u, col0, 0, t + 1);
    SCHEDB();
    __builtin_amdgcn_s_setprio(1); QUAD(a0, b0, 0, 0); __builtin_amdgcn_s_setprio(0);
    BAR();

    // ---- P1: read a1 (for P2, grinds under Q1); Q(a0,b1); BAR
    READ_A(a1, 1, bufo);
    SCHEDB();
    __builtin_amdgcn_s_setprio(1); QUAD(a0, b1, 0, 1); __builtin_amdgcn_s_setprio(0);
    BAR();

    // ---- P2: pure MFMA; BAR
    __builtin_amdgcn_s_setprio(1); QUAD(a1, b1, 1, 1); __builtin_amdgcn_s_setprio(0);
    BAR();

    // ---- P3: stage t+2; VMCNT (tile t+1 landed, every wave); mid-BAR;
    //          read next tile's a0 (grinds under Q3); Q(a1,b0); read next b0
    //          (after b0's last use -> no clobber/overlap). No end barrier.
    if (t < Kt - 2) {
      STAGE(Bg, 32768u, col0, 1, t + 2);
      STAGE(Ag, 0u,     row0, 0, t + 2);
      STAGE(Ag, 0u,     row0, 1, t + 2);
      VMCNT(6);               // completes tile t+1's 4 halves; t+2's 6 in flight
    } else if (t == Kt - 2) {
      VMCNT(0);               // drain: tile Kt-1 fully landed
    }
    BAR();
    if (t < Kt - 1) { READ_A(a0, 0, nbufo); SCHEDB(); }
    __builtin_amdgcn_s_setprio(1); QUAD(a1, b0, 1, 0); __builtin_amdgcn_s_setprio(0);
    if (t < Kt - 1) { READ_B(b0, 0, nbufo); }
  }

  // ---- epilogue: C/D layout col=lane&15, row=(lane>>4)*4+j
  #pragma unroll
  for (int n = 0; n < 4; ++n) {
    const int col = col0 + wn * 64 + n * 16 + l15;
    const float bv = bias[col];
    #pragma unroll
    for (int mi8 = 0; mi8 < 8; ++mi8) {
      #pragma unroll
      for (int j = 0; j < 4; ++j) {
        const int row = row0 + wm * 128 + mi8 * 16 + l16 * 4 + j;
        C[(size_t)row * N + col] = acc[mi8][n][j] + bv;
      }
    }
  }
}

// ---------------- fallback: 128x128 2-phase kernel (round-1, verified) ----------------
template<bool BF16SRC>
__global__ __launch_bounds__(256)
void gemm_bt_kernel(const void* __restrict__ Ap, const void* __restrict__ Bp,
                    const float* __restrict__ bias, float* __restrict__ C,
                    int M, int N, int K)
{
  constexpr int BM = 128, BN = 128, BK = 64;
  __shared__ unsigned short As[BM * BK];
  __shared__ unsigned short Bs[BN * BK];

  const int nTN = N / BN;
  int bid = blockIdx.x;
  const int nwg = gridDim.x;
  if ((nwg & 7) == 0) { const int cpx = nwg >> 3; bid = (bid & 7) * cpx + (bid >> 3); }
  const int tm = bid / nTN, tn = bid % nTN;
  const int row0 = tm * BM, col0 = tn * BN;

  const int tid  = threadIdx.x;
  const int lane = tid & 63;
  const int wid  = tid >> 6;
  const int wm   = wid >> 1;
  const int wn   = wid & 1;

  f32x4 acc[4][4] = {};

  const unsigned short* A16 = (const unsigned short*)Ap;
  const unsigned short* B16 = (const unsigned short*)Bp;
  const float* A32 = (const float*)Ap;
  const float* B32 = (const float*)Bp;

  for (int k0 = 0; k0 < K; k0 += BK) {
    if constexpr (BF16SRC) {
      #pragma unroll
      for (int j = 0; j < 4; ++j) {
        const int c  = wid * 4 + j;
        const int r  = c * 8 + (lane >> 3);
        const int kk = (lane & 7) * 8;
        __builtin_amdgcn_global_load_lds(
            (const __attribute__((address_space(1))) void*)(A16 + (size_t)(row0 + r) * K + k0 + kk),
            (__attribute__((address_space(3))) void*)(&As[c * 512]), 16, 0, 0);
      }
      #pragma unroll
      for (int j = 0; j < 4; ++j) {
        const int c  = wid * 4 + j;
        const int r  = c * 8 + (lane >> 3);
        const int kk = (lane & 7) * 8;
        __builtin_amdgcn_global_load_lds(
            (const __attribute__((address_space(1))) void*)(B16 + (size_t)(col0 + r) * K + k0 + kk),
            (__attribute__((address_space(3))) void*)(&Bs[c * 512]), 16, 0, 0);
      }
    } else {
      #pragma unroll
      for (int j = 0; j < 4; ++j) {
        const int e = (j * 256 + tid) * 8;
        const int r = e >> 6, kk = e & 63;
        floatv4 v0 = *(const floatv4*)&A32[(size_t)(row0 + r) * K + k0 + kk];
        floatv4 v1 = *(const floatv4*)&A32[(size_t)(row0 + r) * K + k0 + kk + 4];
        ushortx8 o;
        o[0] = f2bf(v0[0]); o[1] = f2bf(v0[1]); o[2] = f2bf(v0[2]); o[3] = f2bf(v0[3]);
        o[4] = f2bf(v1[0]); o[5] = f2bf(v1[1]); o[6] = f2bf(v1[2]); o[7] = f2bf(v1[3]);
        *(ushortx8*)&As[e] = o;
      }
      #pragma unroll
      for (int j = 0; j < 4; ++j) {
        const int e = (j * 256 + tid) * 8;
        const int r = e >> 6, kk = e & 63;
        floatv4 v0 = *(const floatv4*)&B32[(size_t)(col0 + r) * K + k0 + kk];
        floatv4 v1 = *(const floatv4*)&B32[(size_t)(col0 + r) * K + k0 + kk + 4];
        ushortx8 o;
        o[0] = f2bf(v0[0]); o[1] = f2bf(v0[1]); o[2] = f2bf(v0[2]); o[3] = f2bf(v0[3]);
        o[4] = f2bf(v1[0]); o[5] = f2bf(v1[1]); o[6] = f2bf(v1[2]); o[7] = f2bf(v1[3]);
        *(ushortx8*)&Bs[e] = o;
      }
    }
    __syncthreads();

    #pragma unroll
    for (int kk = 0; kk < BK / 32; ++kk) {
      const int ko = kk * 32 + (lane >> 4) * 8;
      bf16x8 a[4], b[4];
      #pragma unroll
      for (int mi = 0; mi < 4; ++mi)
        a[mi] = *(const bf16x8*)&As[(wm * 64 + mi * 16 + (lane & 15)) * BK + ko];
      #pragma unroll
      for (int ni = 0; ni < 4; ++ni)
        b[ni] = *(const bf16x8*)&Bs[(wn * 64 + ni * 16 + (lane & 15)) * BK + ko];
      #pragma unroll
      for (int mi = 0; mi < 4; ++mi)
        #pragma unroll
        for (int ni = 0; ni < 4; ++ni)
          acc[mi][ni] = __builtin_amdgcn_mfma_f32_16x16x32_bf16(a[mi], b[ni], acc[mi][ni], 0, 0, 0);
    }
    __syncthreads();
  }

  #pragma unroll
  for (int mi = 0; mi < 4; ++mi) {
    #pragma unroll
    for (int ni = 0; ni < 4; ++ni) {
      const int col = col0 + wn * 64 + ni * 16 + (lane & 15);
      const float bv = bias[col];
      #pragma unroll
      for (int j = 0; j < 4; ++j) {
        const int row = row0 + wm * 64 + mi * 16 + (lane >> 4) * 4 + j;
        C[(size_t)row * N + col] = acc[mi][ni][j] + bv;
      }
    }
  }
}

extern "C" void kernel_launch(void* const* d_in, const int* in_sizes, int n_in,
                              void* d_out, int out_size, void* d_ws, size_t ws_size,
                              hipStream_t stream) {
  const float* x = (const float*)d_in[0];
  const float* w = (const float*)d_in[1];
  const float* b = (const float*)d_in[2];
  float* out = (float*)d_out;

  const int N = in_sizes[2];            // 4096
  const int K = in_sizes[1] / N;        // 4096
  const int M = in_sizes[0] / K;        // 8192

  const size_t needed = ((size_t)M * K + (size_t)N * K) * sizeof(unsigned short);

  if (ws_size >= needed) {
    unsigned short* Abf = (unsigned short*)d_ws;
    unsigned short* Bbf = Abf + (size_t)M * K;
    cvt_f32_to_bf16<<<2048, 256, 0, stream>>>(x, Abf, (size_t)M * K / 8);
    cvt_f32_to_bf16<<<2048, 256, 0, stream>>>(w, Bbf, (size_t)N * K / 8);
    if ((M % 256) == 0 && (N % 256) == 0 && (K % 64) == 0 && K >= 192) {
      const int grid = (M / 256) * (N / 256);
      gemm8p_bt<<<grid, 512, 0, stream>>>(Abf, Bbf, b, out, M, N, K);
    } else {
      const int grid = (M / 128) * (N / 128);
      gemm_bt_kernel<true><<<grid, 256, 0, stream>>>(Abf, Bbf, b, out, M, N, K);
    }
  } else {
    const int grid = (M / 128) * (N / 128);
    gemm_bt_kernel<false><<<grid, 256, 0, stream>>>(x, w, b, out, M, N, K);
  }
}